// Round 15
// baseline (99.757 us; speedup 1.0000x reference)
//
#include <hip/hip_runtime.h>

// Barrier-free, LDS-free scanline Laplacian-pyramid level — float4-per-lane.
// Wave = 256-px strip x sh rows; lane owns 4 pixel cols (c0..c0+3) and 2 down
// cols. Rolling 5-row float4 window + depth-1 prefetch (R13 structure, which
// beat depth-2: R14 showed the kernel is instruction-issue-bound, not
// latency-bound — so this round halves instructions/byte instead of adding
// in-flight bytes). Strip-edge halo float4 lives in lanes 0/63's own second
// window: horizontal taps need only 5 shuffles/row, no broadcasts.
// Chain-convention halo down values (reflect inherited from reflected loads +
// kernel symmetry) — exactly what the up-stencil needs (validated R3-R13).

__device__ __forceinline__ int refl(int t, int n) {
    if (t < 0) t = -t;
    if (t >= n) t = 2 * (n - 1) - t;
    return t;
}

__global__ __launch_bounds__(256, 5) void lap_scan_kernel(
    const float* __restrict__ cur, float* __restrict__ lap,
    float* __restrict__ down, int H, int W, int sh)
{
    const int wid = threadIdx.x >> 6, lane = threadIdx.x & 63;
    const int x0 = blockIdx.x * 256;
    const int y0 = (blockIdx.y * 4 + wid) * sh;
    const int img = blockIdx.z;
    const int Hh = H >> 1, Wh = W >> 1;

    const float* curb = cur + (size_t)img * H * W;
    float* lapb = lap + (size_t)img * H * W;
    float* downb = down + (size_t)img * Hh * Wh;

    const int c0 = x0 + 4 * lane;                     // own 4 pixel cols (in-image)
    const bool haloLane = (lane == 0) | (lane == 63);
    const int hc0 = (lane == 0) ? (x0 - 4) : (x0 + 256);   // halo 4-col base
    const bool xb = (x0 == 0) || (x0 + 256 == W);
    int hg0 = refl(hc0, W), hg1 = refl(hc0 + 1, W),
        hg2 = refl(hc0 + 2, W), hg3 = refl(hc0 + 3, W);

    auto loadOwn = [&](int rho) -> float4 {
        return *(const float4*)(curb + (size_t)refl(y0 + rho, H) * W + c0);
    };
    auto loadHalo = [&](int rho) -> float4 {
        const float* rp = curb + (size_t)refl(y0 + rho, H) * W;
        float4 v;
        if (xb) { v.x = rp[hg0]; v.y = rp[hg1]; v.z = rp[hg2]; v.w = rp[hg3]; }
        else    { v = *(const float4*)(rp + hc0); }    // 16B-aligned (x0-4 offset)
        return v;
    };

    // prologue: rows y0-4 .. y0 (iteration a uses pixel rows 2a-2..2a+2)
    float4 w0 = loadOwn(-4), w1 = loadOwn(-3), w2 = loadOwn(-2),
           w3 = loadOwn(-1), w4 = loadOwn(0);
    float4 z4 = {0.f, 0.f, 0.f, 0.f};
    float4 h0 = z4, h1 = z4, h2 = z4, h3 = z4, h4 = z4;
    if (haloLane) {
        h0 = loadHalo(-4); h1 = loadHalo(-3); h2 = loadHalo(-2);
        h3 = loadHalo(-1); h4 = loadHalo(0);
    }

    // rolling down-row state: rel down cols 2l-1 .. 2l+2 for rows a-2, a-1
    float qm20 = 0, qm21 = 0, qm22 = 0, qm23 = 0;
    float qm10 = 0, qm11 = 0, qm12 = 0, qm13 = 0;
    const int aEnd = sh >> 1;

    for (int a = -1; a <= aEnd; ++a) {
        // 1. prefetch next row pair (drains under this iteration's math)
        float4 nw3 = z4, nw4 = z4, nh3 = z4, nh4 = z4;
        const bool more = (a < aEnd);
        if (more) {
            nw3 = loadOwn(2 * a + 3); nw4 = loadOwn(2 * a + 4);
            if (haloLane) { nh3 = loadHalo(2 * a + 3); nh4 = loadHalo(2 * a + 4); }
        }

        // 2. vertical 5-tap, own 4 cols + halo 4 cols
        float vE0 = w0.x + 4.f * w1.x + 6.f * w2.x + 4.f * w3.x + w4.x;
        float vO0 = w0.y + 4.f * w1.y + 6.f * w2.y + 4.f * w3.y + w4.y;
        float vE1 = w0.z + 4.f * w1.z + 6.f * w2.z + 4.f * w3.z + w4.z;
        float vO1 = w0.w + 4.f * w1.w + 6.f * w2.w + 4.f * w3.w + w4.w;
        float hE0 = h0.x + 4.f * h1.x + 6.f * h2.x + 4.f * h3.x + h4.x;
        float hO0 = h0.y + 4.f * h1.y + 6.f * h2.y + 4.f * h3.y + h4.y;
        float hE1 = h0.z + 4.f * h1.z + 6.f * h2.z + 4.f * h3.z + h4.z;
        float hO1 = h0.w + 4.f * h1.w + 6.f * h2.w + 4.f * h3.w + h4.w;

        // 3. horizontal 5-tap -> two down values (rel cols 2l, 2l+1)
        float pE1 = __shfl_up(vE1, 1);    // t(c0-2)
        float pO1 = __shfl_up(vO1, 1);    // t(c0-1)
        float nE0 = __shfl_down(vE0, 1);  // t(c0+4)
        if (lane == 0)  { pE1 = hE1; pO1 = hO1; }
        if (lane == 63) { nE0 = hE0; }
        float d0 = (pE1 + 4.f * pO1 + 6.f * vE0 + 4.f * vO0 + vE1) * (1.f / 256.f);
        float d1 = (vE0 + 4.f * vO0 + 6.f * vE1 + 4.f * vO1 + nE0) * (1.f / 256.f);

        // 4. neighbor exchange: q0..q3 = down rel cols 2l-1, 2l, 2l+1, 2l+2
        float q0 = __shfl_up(d1, 1);
        float q3 = __shfl_down(d0, 1);
        if (lane == 0)    // rel col -1 (center px x0-2): all taps lane-local
            q0 = (hE0 + 4.f * hO0 + 6.f * hE1 + 4.f * hO1 + vE0) * (1.f / 256.f);
        if (lane == 63)   // rel col 128 (center px x0+256): lane-local
            q3 = (vE1 + 4.f * vO1 + 6.f * hE0 + 4.f * hO0 + hE1) * (1.f / 256.f);
        float q1 = d0, q2 = d1;

        // 5. store down row (interior rows only)
        if (a >= 0 && a < aEnd) {
            float2 dd; dd.x = d0; dd.y = d1;
            *(float2*)(downb + (size_t)((y0 >> 1) + a) * Wh + (x0 >> 1) + 2 * lane) = dd;
        }

        // 6. emit lap rows y0+2a-2 (=w0) and y0+2a-1 (=w1)
        if (a >= 1) {
            float CE0 = qm20 + 6.f * qm10 + q0;
            float CE1 = qm21 + 6.f * qm11 + q1;
            float CE2 = qm22 + 6.f * qm12 + q2;
            float CE3 = qm23 + 6.f * qm13 + q3;
            float CO0 = 4.f * (qm10 + q0);
            float CO1 = 4.f * (qm11 + q1);
            float CO2 = 4.f * (qm12 + q2);
            float CO3 = 4.f * (qm13 + q3);
            float4 oe, oo;
            oe.x = w0.x - (CE0 + 6.f * CE1 + CE2) * (1.f / 64.f);
            oe.y = w0.y - 4.f * (CE1 + CE2) * (1.f / 64.f);
            oe.z = w0.z - (CE1 + 6.f * CE2 + CE3) * (1.f / 64.f);
            oe.w = w0.w - 4.f * (CE2 + CE3) * (1.f / 64.f);
            oo.x = w1.x - (CO0 + 6.f * CO1 + CO2) * (1.f / 64.f);
            oo.y = w1.y - 4.f * (CO1 + CO2) * (1.f / 64.f);
            oo.z = w1.z - (CO1 + 6.f * CO2 + CO3) * (1.f / 64.f);
            oo.w = w1.w - 4.f * (CO2 + CO3) * (1.f / 64.f);
            *(float4*)(lapb + (size_t)(y0 + 2 * a - 2) * W + c0) = oe;
            *(float4*)(lapb + (size_t)(y0 + 2 * a - 1) * W + c0) = oo;
        }

        // 7. shift rolling state by one row-pair
        qm20 = qm10; qm21 = qm11; qm22 = qm12; qm23 = qm13;
        qm10 = q0;   qm11 = q1;   qm12 = q2;   qm13 = q3;
        w0 = w2; w1 = w3; w2 = w4;
        h0 = h2; h1 = h3; h2 = h4;
        if (more) { w3 = nw3; w4 = nw4; h3 = nh3; h4 = nh4; }
    }
}

extern "C" void kernel_launch(void* const* d_in, const int* in_sizes, int n_in,
                              void* d_out, int out_size, void* d_ws, size_t ws_size,
                              hipStream_t stream) {
    const float* img = (const float*)d_in[0];
    float* out = (float*)d_out;

    const long long BC = 8LL * 3;
    const long long n0 = BC * 1024 * 1024;
    const long long n1 = BC * 512 * 512;
    const long long n2 = BC * 256 * 256;

    float* out0 = out;            // lap0
    float* out1 = out0 + n0;      // lap1
    float* out2 = out1 + n1;      // lap2
    float* out3 = out2 + n2;      // down2

    float* ws0 = (float*)d_ws;    // down0
    float* ws1 = ws0 + n1;        // down1

    // grid: (W/256 strips, H/(4*sh) wave-quads, 24 images)
    lap_scan_kernel<<<dim3(1024 / 256, 1024 / (4 * 32), (int)BC), 256, 0, stream>>>(
        img, out0, ws0, 1024, 1024, 32);
    lap_scan_kernel<<<dim3(512 / 256, 512 / (4 * 8), (int)BC), 256, 0, stream>>>(
        ws0, out1, ws1, 512, 512, 8);
    lap_scan_kernel<<<dim3(256 / 256, 256 / (4 * 4), (int)BC), 256, 0, stream>>>(
        ws1, out2, out3, 256, 256, 4);
}